// Round 9
// baseline (7522.363 us; speedup 1.0000x reference)
//
#include <hip/hip_runtime.h>
#include <hip/hip_bf16.h>

#define SEQ 512
#define BATCH 64
#define IN_DIM 512
#define HID 1024
#define G3 3072          // 3*HID
#define MTOT 32768       // SEQ*BATCH
#define NWG 128

typedef float f32x4 __attribute__((ext_vector_type(4)));
typedef short s16x8 __attribute__((ext_vector_type(8)));

static __device__ __forceinline__ unsigned short f2bf(float f) {
  union { float f; unsigned u; } v; v.f = f;
  unsigned r = v.u + 0x7fffu + ((v.u >> 16) & 1u);
  return (unsigned short)(r >> 16);
}
static __device__ __forceinline__ float bf2f(unsigned short b) {
  union { unsigned u; float f; } v; v.u = ((unsigned)b) << 16;
  return v.f;
}
static __device__ __forceinline__ unsigned umin2(unsigned a, unsigned b) { return a < b ? a : b; }

// ---------------- fp32 -> bf16 hi/lo split ----------------
__global__ __launch_bounds__(256) void split_kernel(const float* __restrict__ src,
    unsigned short* __restrict__ hi, unsigned short* __restrict__ lo, int n4) {
  int stride = gridDim.x * blockDim.x;
  for (int i = blockIdx.x * blockDim.x + threadIdx.x; i < n4; i += stride) {
    float4 v = ((const float4*)src)[i];
    ushort4 h, l;
    h.x = f2bf(v.x); l.x = f2bf(v.x - bf2f(h.x));
    h.y = f2bf(v.y); l.y = f2bf(v.y - bf2f(h.y));
    h.z = f2bf(v.z); l.z = f2bf(v.z - bf2f(h.z));
    h.w = f2bf(v.w); l.w = f2bf(v.w - bf2f(h.w));
    ((ushort4*)hi)[i] = h;
    ((ushort4*)lo)[i] = l;
  }
}

// ---------------- phase 1: gi = emb @ w_ih^T + b_ih  (3-pass hi/lo split) ----
__global__ __launch_bounds__(256) void gemm_gi(
    const unsigned short* __restrict__ Ahi, const unsigned short* __restrict__ Alo,
    const unsigned short* __restrict__ Bhi, const unsigned short* __restrict__ Blo,
    const float* __restrict__ bih,
    float* __restrict__ gi32, unsigned short* __restrict__ gi16, int gi_is_f32)
{
  __shared__ unsigned short Al[128 * 64];
  __shared__ unsigned short Bl[128 * 64];
  const int tid = threadIdx.x;
  const int wave = tid >> 6, lane = tid & 63;
  const int bm0 = blockIdx.x * 128, bn0 = blockIdx.y * 128;
  const int wm = (wave >> 1) * 64, wn = (wave & 1) * 64;
  const int row16 = lane & 15, kq = lane >> 4;
  const int srow = tid >> 3;
  const int skc = tid & 7;

  f32x4 acc[4][4] = {};
  for (int p = 0; p < 3; ++p) {
    const unsigned short* Ap = (p == 1) ? Alo : Ahi;
    const unsigned short* Bp = (p == 2) ? Blo : Bhi;
    for (int kt = 0; kt < IN_DIM / 64; ++kt) {
      uint4 ar[4], br[4];
      for (int i = 0; i < 4; ++i) {
        int r = i * 32 + srow;
        ar[i] = *(const uint4*)&Ap[(size_t)(bm0 + r) * IN_DIM + kt * 64 + skc * 8];
        br[i] = *(const uint4*)&Bp[(size_t)(bn0 + r) * IN_DIM + kt * 64 + skc * 8];
      }
      __syncthreads();
      for (int i = 0; i < 4; ++i) {
        int r = i * 32 + srow;
        *(uint4*)&Al[r * 64 + skc * 8] = ar[i];
        *(uint4*)&Bl[r * 64 + skc * 8] = br[i];
      }
      __syncthreads();
      for (int kk = 0; kk < 2; ++kk) {
        s16x8 af[4], bf[4];
        for (int mi = 0; mi < 4; ++mi)
          af[mi] = *(const s16x8*)&Al[(wm + mi * 16 + row16) * 64 + kk * 32 + kq * 8];
        for (int ni = 0; ni < 4; ++ni)
          bf[ni] = *(const s16x8*)&Bl[(wn + ni * 16 + row16) * 64 + kk * 32 + kq * 8];
        for (int mi = 0; mi < 4; ++mi)
          for (int ni = 0; ni < 4; ++ni)
            acc[mi][ni] = __builtin_amdgcn_mfma_f32_16x16x32_bf16(af[mi], bf[ni], acc[mi][ni], 0, 0, 0);
      }
    }
  }
  for (int mi = 0; mi < 4; ++mi) {
    int grow0 = bm0 + wm + mi * 16 + kq * 4;
    for (int ni = 0; ni < 4; ++ni) {
      int gcol = bn0 + wn + ni * 16 + row16;
      float bias = bih[gcol];
#pragma unroll
      for (int q = 0; q < 4; ++q) {
        float v = acc[mi][ni][q] + bias;
        size_t off = (size_t)(grow0 + q) * G3 + gcol;
        if (gi_is_f32) gi32[off] = v;
        else gi16[off] = f2bf(v);
      }
    }
  }
}

// ---------------- persistent GRU scan: tagged-dword dataflow ----------------
// 128 WGs x 512 thr. WG owns 8 hidden units (24 w_hh HI rows in LDS, staged once).
// Waves: mt = wave&3 (16-batch tile), kh = wave>>2 (K half).
// NO grid barrier. h element = dword (bf16 << 16) | step_tag. Producer's store
// IS the signal. Consumer loads its slice (32 dwordx4, sc0 sc1), checks min tag
// over all 128 dwords == step, retries on stale. Safety:
//  - dword stores are atomic; every element carries its own tag.
//  - 2-buffer reuse safe: producer at step t (overwriting h_{t-2}) has observed
//    all tags of h_{t-1}; each h_{t-1} store was issued only after that WG's
//    h_{t-2} loads retired (vmcnt(0) + data deps) -> no read-write race.
//  - tags monotonic; a producer can't be 2 steps ahead of a live same-buffer
//    reader (it would need all of h_{t-1} first).
// sc0sc1 store -> poll-load coherence across XCDs proven by rounds 6-8.

#define LDT(dst, OFFS) asm volatile("global_load_dwordx4 %0, %1, off offset:" OFFS " sc0 sc1" : "=v"(dst) : "v"(hadr))
#define WAITV(N) do { asm volatile("s_waitcnt vmcnt(" #N ")" ::: "memory"); __builtin_amdgcn_sched_barrier(0); } while (0)
#define TMIN(v) mn = umin2(mn, umin2(umin2(v.x & 0xffffu, v.y & 0xffffu), umin2(v.z & 0xffffu, v.w & 0xffffu)))
#define PKHI(a, b) (((a) >> 16) | ((b) & 0xffff0000u))
#define MMK(AH, KIDX) do { \
    int wb = (kh << 10) + (KIDX) * 64 + (kq << 4); \
    s16x8 wh0 = *(const s16x8*)(wbase + (cc0 << 11) + (wb ^ xr)); \
    s16x8 wh1 = *(const s16x8*)(wbase + (cc1 << 11) + (wb ^ xr)); \
    acc0 = __builtin_amdgcn_mfma_f32_16x16x32_bf16(AH, wh0, acc0, 0, 0, 0); \
    acc1 = __builtin_amdgcn_mfma_f32_16x16x32_bf16(AH, wh1, acc1, 0, 0, 0); \
  } while (0)
#define MMKT(U, V, KIDX) do { \
    union { unsigned d[4]; s16x8 v8; } _a; \
    _a.d[0] = PKHI(U.x, U.y); _a.d[1] = PKHI(U.z, U.w); \
    _a.d[2] = PKHI(V.x, V.y); _a.d[3] = PKHI(V.z, V.w); \
    MMK(_a.v8, KIDX); } while (0)

__global__ __launch_bounds__(512, 2) void gru_persist(
    const unsigned short* __restrict__ Whh_hi,
    const float* __restrict__ gi32, const unsigned short* __restrict__ gi16, int gi_is_f32,
    const float* __restrict__ bhh,
    unsigned* __restrict__ hd0, unsigned* __restrict__ hd1,
    float* __restrict__ out, float* __restrict__ hidden)
{
  __shared__ unsigned short wl[2 * 24 * 1024];  // 96KB declared (pins 1 WG/CU); hi half used
  __shared__ float ghl2[2][64][24];             // 12KB (K-split partials)
  __shared__ float hown[512];                   // own h slice, fp32
  const int tid = threadIdx.x;
  const int wg = blockIdx.x;
  const int j0 = wg * 8;

  // stage w_hh HI once: 24 rows x 1024 elems = 3072 16B-chunks, 6 per thread
  for (int i = 0; i < 6; ++i) {
    int c = i * 512 + tid;
    int col = c >> 7;
    int kb = c & 127;
    int gate = col >> 3, uu = col & 7;
    const unsigned short* src = Whh_hi + (size_t)(gate * HID + j0 + uu) * HID + kb * 8;
    int byte = col * 2048 + ((kb * 16) ^ ((col & 7) << 4));
    *(uint4*)((char*)wl + byte) = *(const uint4*)src;
  }
  hown[tid] = 0.f;

  const int wave = tid >> 6, lane = tid & 63;
  const int mt = wave & 3, kh = wave >> 2;
  const int row16 = lane & 15, kq = lane >> 4;
  const int b = mt * 16 + row16;
  const int cc0 = row16;
  const int cc1 = 16 + (row16 & 7);
  const int xr = (row16 & 7) << 4;
  const char* wbase = (const char*)wl;
  const unsigned hvoff = (unsigned)(b * 4096 + kh * 2048 + kq * 32);  // dword h layout

  const int b2 = tid >> 3, u = tid & 7, j = j0 + u;
  const float bh_r = bhh[j], bh_z = bhh[HID + j], bh_n = bhh[2 * HID + j];

  __syncthreads();

  for (int s = 0; s < SEQ; ++s) {
    const unsigned* hd_in = (s & 1) ? hd1 : hd0;
    unsigned* hd_out = (s & 1) ? hd0 : hd1;
    unsigned long long hadr = (unsigned long long)hd_in + hvoff;
    const unsigned exp = (unsigned)s;   // tag of h_s

    // gi prefetch (independent of h)
    float gir = 0.f, giz = 0.f, gin_ = 0.f;
    unsigned short g16r = 0, g16z = 0, g16n = 0;
    if (gi_is_f32) {
      unsigned long long ga = (unsigned long long)(gi32 + (size_t)(s * BATCH + b2) * G3 + j);
      asm volatile("global_load_dword %0, %1, off" : "=v"(gir) : "v"(ga));
      asm volatile("global_load_dword %0, %1, off" : "=v"(giz) : "v"(ga + 4096ull));
      asm volatile("global_load_dword %0, %1, off" : "=v"(gin_) : "v"(ga + 8192ull));
    } else {
      unsigned long long ga = (unsigned long long)(gi16 + (size_t)(s * BATCH + b2) * G3 + j);
      asm volatile("global_load_ushort %0, %1, off" : "=v"(g16r) : "v"(ga));
      asm volatile("global_load_ushort %0, %1, off" : "=v"(g16z) : "v"(ga + 2048ull));
      asm volatile("global_load_ushort %0, %1, off" : "=v"(g16n) : "v"(ga + 4096ull));
    }

    // dataflow wait: load full slice, verify ALL tags, retry if any stale
    uint4 u0, u1, u2, u3, u4, u5, u6, u7, u8, u9, u10, u11, u12, u13, u14, u15;
    uint4 u16_, u17, u18, u19, u20, u21, u22, u23, u24, u25, u26, u27, u28, u29, u30, u31;
    for (;;) {
      LDT(u0, "0");     LDT(u1, "16");    LDT(u2, "128");   LDT(u3, "144");
      LDT(u4, "256");   LDT(u5, "272");   LDT(u6, "384");   LDT(u7, "400");
      LDT(u8, "512");   LDT(u9, "528");   LDT(u10, "640");  LDT(u11, "656");
      LDT(u12, "768");  LDT(u13, "784");  LDT(u14, "896");  LDT(u15, "912");
      LDT(u16_, "1024"); LDT(u17, "1040"); LDT(u18, "1152"); LDT(u19, "1168");
      LDT(u20, "1280"); LDT(u21, "1296"); LDT(u22, "1408"); LDT(u23, "1424");
      LDT(u24, "1536"); LDT(u25, "1552"); LDT(u26, "1664"); LDT(u27, "1680");
      LDT(u28, "1792"); LDT(u29, "1808"); LDT(u30, "1920"); LDT(u31, "1936");
      WAITV(0);
      unsigned mn = 0xffffffffu;
      TMIN(u0);  TMIN(u1);  TMIN(u2);  TMIN(u3);  TMIN(u4);  TMIN(u5);  TMIN(u6);  TMIN(u7);
      TMIN(u8);  TMIN(u9);  TMIN(u10); TMIN(u11); TMIN(u12); TMIN(u13); TMIN(u14); TMIN(u15);
      TMIN(u16_); TMIN(u17); TMIN(u18); TMIN(u19); TMIN(u20); TMIN(u21); TMIN(u22); TMIN(u23);
      TMIN(u24); TMIN(u25); TMIN(u26); TMIN(u27); TMIN(u28); TMIN(u29); TMIN(u30); TMIN(u31);
      if (__all((int)(mn >= exp))) break;
    }

    // unpack + MFMA
    f32x4 acc0 = {0.f, 0.f, 0.f, 0.f}, acc1 = {0.f, 0.f, 0.f, 0.f};
    MMKT(u0, u1, 0);    MMKT(u2, u3, 1);    MMKT(u4, u5, 2);    MMKT(u6, u7, 3);
    MMKT(u8, u9, 4);    MMKT(u10, u11, 5);  MMKT(u12, u13, 6);  MMKT(u14, u15, 7);
    MMKT(u16_, u17, 8); MMKT(u18, u19, 9);  MMKT(u20, u21, 10); MMKT(u22, u23, 11);
    MMKT(u24, u25, 12); MMKT(u26, u27, 13); MMKT(u28, u29, 14); MMKT(u30, u31, 15);

#pragma unroll
    for (int q = 0; q < 4; ++q)
      ghl2[kh][mt * 16 + kq * 4 + q][row16] = acc0[q];
    if (row16 < 8) {
#pragma unroll
      for (int q = 0; q < 4; ++q)
        ghl2[kh][mt * 16 + kq * 4 + q][16 + row16] = acc1[q];
    }
    __syncthreads();

    // gating
    float ir, iz, inn;
    if (gi_is_f32) { ir = gir; iz = giz; inn = gin_; }
    else { ir = bf2f(g16r); iz = bf2f(g16z); inn = bf2f(g16n); }
    float hr = ghl2[0][b2][u]      + ghl2[1][b2][u]      + bh_r;
    float hz = ghl2[0][b2][8 + u]  + ghl2[1][b2][8 + u]  + bh_z;
    float hn = ghl2[0][b2][16 + u] + ghl2[1][b2][16 + u] + bh_n;
    float r = 1.f / (1.f + __expf(-(ir + hr)));
    float z = 1.f / (1.f + __expf(-(iz + hz)));
    float n = tanhf(inn + r * hn);
    float hp = hown[tid];
    float h = (1.f - z) * n + z * hp;
    hown[tid] = h;
    // tagged h store: the data IS the barrier signal
    unsigned dv = ((unsigned)f2bf(h) << 16) | (unsigned)(s + 1);
    unsigned long long sha = (unsigned long long)hd_out + (unsigned)(b2 * 1024 + j) * 4u;
    asm volatile("global_store_dword %0, %1, off sc0 sc1" :: "v"(sha), "v"(dv) : "memory");
    out[((size_t)b2 * SEQ + s) * HID + j] = h;
    if (s == SEQ - 1) hidden[(size_t)b2 * HID + j] = h;
    __syncthreads();   // ghl2 reuse guard (next step overwrites)
  }
}

extern "C" void kernel_launch(void* const* d_in, const int* in_sizes, int n_in,
                              void* d_out, int out_size, void* d_ws, size_t ws_size,
                              hipStream_t stream) {
  const float* emb = (const float*)d_in[0];
  const float* wih = (const float*)d_in[1];
  const float* whh = (const float*)d_in[2];
  const float* bih = (const float*)d_in[3];
  const float* bhh = (const float*)d_in[4];
  float* out = (float*)d_out;                          // [64][512][1024]
  float* hidden = out + (size_t)BATCH * SEQ * HID;     // [64][1024]

  char* ws = (char*)d_ws;
  size_t off = 0;
  auto alloc = [&](size_t bytes) {
    char* p = ws + off;
    off += (bytes + 255) & ~(size_t)255;
    return p;
  };

  unsigned short* emb_hi = (unsigned short*)alloc((size_t)MTOT * IN_DIM * 2);
  unsigned short* emb_lo = (unsigned short*)alloc((size_t)MTOT * IN_DIM * 2);
  unsigned short* wih_hi = (unsigned short*)alloc((size_t)G3 * IN_DIM * 2);
  unsigned short* wih_lo = (unsigned short*)alloc((size_t)G3 * IN_DIM * 2);
  unsigned short* whh_hi = (unsigned short*)alloc((size_t)G3 * HID * 2);
  unsigned short* whh_lo = (unsigned short*)alloc((size_t)G3 * HID * 2);
  unsigned* hbuf = (unsigned*)alloc((size_t)2 * BATCH * HID * 4);   // 2 tagged buffers

  size_t gi32_bytes = (size_t)MTOT * G3 * 4;
  int gi_is_f32 = (off + gi32_bytes <= ws_size) ? 1 : 0;
  float* gi32 = nullptr;
  unsigned short* gi16 = nullptr;
  if (gi_is_f32) gi32 = (float*)alloc(gi32_bytes);
  else           gi16 = (unsigned short*)alloc((size_t)MTOT * G3 * 2);

  // converts
  split_kernel<<<4096, 256, 0, stream>>>(emb, emb_hi, emb_lo, MTOT * IN_DIM / 4);
  split_kernel<<<1536, 256, 0, stream>>>(wih, wih_hi, wih_lo, G3 * IN_DIM / 4);
  split_kernel<<<3072, 256, 0, stream>>>(whh, whh_hi, whh_lo, G3 * HID / 4);

  // zero tagged h buffers: h_0 = 0 with tag 0 (must reset every call/replay)
  (void)hipMemsetAsync(hbuf, 0, (size_t)2 * BATCH * HID * 4, stream);

  // phase 1 GEMM
  dim3 g1(MTOT / 128, G3 / 128);
  gemm_gi<<<g1, 256, 0, stream>>>(emb_hi, emb_lo, wih_hi, wih_lo, bih, gi32, gi16, gi_is_f32);

  // persistent scan (cooperative: guarantees all 128 WGs co-resident)
  unsigned* hd0 = hbuf;
  unsigned* hd1 = hbuf + (size_t)BATCH * HID;
  void* args[] = { &whh_hi, &gi32, &gi16, &gi_is_f32, &bhh,
                   &hd0, &hd1, &out, &hidden };
  (void)hipLaunchCooperativeKernel((void*)gru_persist, dim3(NWG), dim3(512), args, 0, stream);
}

// Round 10
// 4993.855 us; speedup vs baseline: 1.5063x; 1.5063x over previous
//
#include <hip/hip_runtime.h>
#include <hip/hip_bf16.h>

#define SEQ 512
#define BATCH 64
#define IN_DIM 512
#define HID 1024
#define G3 3072          // 3*HID
#define MTOT 32768       // SEQ*BATCH
#define NWG 128

typedef float f32x4 __attribute__((ext_vector_type(4)));
typedef short s16x8 __attribute__((ext_vector_type(8)));

static __device__ __forceinline__ unsigned short f2bf(float f) {
  union { float f; unsigned u; } v; v.f = f;
  unsigned r = v.u + 0x7fffu + ((v.u >> 16) & 1u);
  return (unsigned short)(r >> 16);
}
static __device__ __forceinline__ float bf2f(unsigned short b) {
  union { unsigned u; float f; } v; v.u = ((unsigned)b) << 16;
  return v.f;
}
static __device__ __forceinline__ unsigned umin2(unsigned a, unsigned b) { return a < b ? a : b; }

// ---------------- fp32 -> bf16 hi/lo split ----------------
__global__ __launch_bounds__(256) void split_kernel(const float* __restrict__ src,
    unsigned short* __restrict__ hi, unsigned short* __restrict__ lo, int n4) {
  int stride = gridDim.x * blockDim.x;
  for (int i = blockIdx.x * blockDim.x + threadIdx.x; i < n4; i += stride) {
    float4 v = ((const float4*)src)[i];
    ushort4 h, l;
    h.x = f2bf(v.x); l.x = f2bf(v.x - bf2f(h.x));
    h.y = f2bf(v.y); l.y = f2bf(v.y - bf2f(h.y));
    h.z = f2bf(v.z); l.z = f2bf(v.z - bf2f(h.z));
    h.w = f2bf(v.w); l.w = f2bf(v.w - bf2f(h.w));
    ((ushort4*)hi)[i] = h;
    ((ushort4*)lo)[i] = l;
  }
}

// ---------------- phase 1: gi = emb @ w_ih^T + b_ih  (3-pass hi/lo split) ----
__global__ __launch_bounds__(256) void gemm_gi(
    const unsigned short* __restrict__ Ahi, const unsigned short* __restrict__ Alo,
    const unsigned short* __restrict__ Bhi, const unsigned short* __restrict__ Blo,
    const float* __restrict__ bih,
    float* __restrict__ gi32, unsigned short* __restrict__ gi16, int gi_is_f32)
{
  __shared__ unsigned short Al[128 * 64];
  __shared__ unsigned short Bl[128 * 64];
  const int tid = threadIdx.x;
  const int wave = tid >> 6, lane = tid & 63;
  const int bm0 = blockIdx.x * 128, bn0 = blockIdx.y * 128;
  const int wm = (wave >> 1) * 64, wn = (wave & 1) * 64;
  const int row16 = lane & 15, kq = lane >> 4;
  const int srow = tid >> 3;
  const int skc = tid & 7;

  f32x4 acc[4][4] = {};
  for (int p = 0; p < 3; ++p) {
    const unsigned short* Ap = (p == 1) ? Alo : Ahi;
    const unsigned short* Bp = (p == 2) ? Blo : Bhi;
    for (int kt = 0; kt < IN_DIM / 64; ++kt) {
      uint4 ar[4], br[4];
      for (int i = 0; i < 4; ++i) {
        int r = i * 32 + srow;
        ar[i] = *(const uint4*)&Ap[(size_t)(bm0 + r) * IN_DIM + kt * 64 + skc * 8];
        br[i] = *(const uint4*)&Bp[(size_t)(bn0 + r) * IN_DIM + kt * 64 + skc * 8];
      }
      __syncthreads();
      for (int i = 0; i < 4; ++i) {
        int r = i * 32 + srow;
        *(uint4*)&Al[r * 64 + skc * 8] = ar[i];
        *(uint4*)&Bl[r * 64 + skc * 8] = br[i];
      }
      __syncthreads();
      for (int kk = 0; kk < 2; ++kk) {
        s16x8 af[4], bf[4];
        for (int mi = 0; mi < 4; ++mi)
          af[mi] = *(const s16x8*)&Al[(wm + mi * 16 + row16) * 64 + kk * 32 + kq * 8];
        for (int ni = 0; ni < 4; ++ni)
          bf[ni] = *(const s16x8*)&Bl[(wn + ni * 16 + row16) * 64 + kk * 32 + kq * 8];
        for (int mi = 0; mi < 4; ++mi)
          for (int ni = 0; ni < 4; ++ni)
            acc[mi][ni] = __builtin_amdgcn_mfma_f32_16x16x32_bf16(af[mi], bf[ni], acc[mi][ni], 0, 0, 0);
      }
    }
  }
  for (int mi = 0; mi < 4; ++mi) {
    int grow0 = bm0 + wm + mi * 16 + kq * 4;
    for (int ni = 0; ni < 4; ++ni) {
      int gcol = bn0 + wn + ni * 16 + row16;
      float bias = bih[gcol];
#pragma unroll
      for (int q = 0; q < 4; ++q) {
        float v = acc[mi][ni][q] + bias;
        size_t off = (size_t)(grow0 + q) * G3 + gcol;
        if (gi_is_f32) gi32[off] = v;
        else gi16[off] = f2bf(v);
      }
    }
  }
}

// ---------------- persistent GRU scan (round-8 structure + W-in-VGPR) -------
// 128 WGs x 512 thr. WG owns 8 hidden units (24 w_hh HI rows). W is staged to
// LDS once, then each lane hoists its 32 16B MFMA fragments into VGPRs (128
// VGPRs) -- the steady-state K-loop does ZERO LDS reads: global h load -> MFMA
// with both operands in registers. (Round-8 LDS W-stream was ~1.75us/step
// serialized on the LDS pipe, 4x redundant across mt-waves.)
// Waves: mt = wave&3 (16-batch tile), kh = wave>>2 (K half).
// h broadcast: bf16 hi only. Barrier: flat relaxed monotonic (round 8).

#define LDH(dst, OFFS) asm volatile("global_load_dwordx4 %0, %1, off offset:" OFFS " sc0 sc1" : "=v"(dst) : "v"(hadr))
#define WAITV(N) do { asm volatile("s_waitcnt vmcnt(" #N ")" ::: "memory"); __builtin_amdgcn_sched_barrier(0); } while (0)
#define MMK(AH, KIDX) do { \
    acc0 = __builtin_amdgcn_mfma_f32_16x16x32_bf16(AH, wr[2*(KIDX)], acc0, 0, 0, 0); \
    acc1 = __builtin_amdgcn_mfma_f32_16x16x32_bf16(AH, wr[2*(KIDX)+1], acc1, 0, 0, 0); \
  } while (0)

__global__ __launch_bounds__(512, 2) void gru_persist(
    const unsigned short* __restrict__ Whh_hi,
    const float* __restrict__ gi32, const unsigned short* __restrict__ gi16, int gi_is_f32,
    const float* __restrict__ bhh,
    unsigned short* __restrict__ h0hi, unsigned short* __restrict__ h1hi,
    unsigned* __restrict__ bar,
    float* __restrict__ out, float* __restrict__ hidden)
{
  __shared__ unsigned short wl[2 * 24 * 1024];  // 96KB declared (pins 1 WG/CU); hi half used
  __shared__ float ghl2[2][64][24];             // 12KB (K-split partials)
  __shared__ float hown[512];                   // own h slice, fp32
  const int tid = threadIdx.x;
  const int wg = blockIdx.x;
  const int j0 = wg * 8;

  // stage w_hh HI once: 24 rows x 1024 elems = 3072 16B-chunks, 6 per thread
  for (int i = 0; i < 6; ++i) {
    int c = i * 512 + tid;
    int col = c >> 7;
    int kb = c & 127;
    int gate = col >> 3, uu = col & 7;
    const unsigned short* src = Whh_hi + (size_t)(gate * HID + j0 + uu) * HID + kb * 8;
    int byte = col * 2048 + ((kb * 16) ^ ((col & 7) << 4));
    *(uint4*)((char*)wl + byte) = *(const uint4*)src;
  }
  hown[tid] = 0.f;

  const int wave = tid >> 6, lane = tid & 63;
  const int mt = wave & 3, kh = wave >> 2;
  const int row16 = lane & 15, kq = lane >> 4;
  const int b = mt * 16 + row16;
  const int cc0 = row16;
  const int cc1 = 16 + (row16 & 7);
  const int xr = (row16 & 7) << 4;
  const char* wbase = (const char*)wl;
  const unsigned hvoff = (unsigned)(b * 2048 + kh * 1024 + kq * 16);

  const int b2 = tid >> 3, u = tid & 7, j = j0 + u;
  const float bh_r = bhh[j], bh_z = bhh[HID + j], bh_n = bhh[2 * HID + j];

  unsigned* cA = bar;            // 8 monotonic counters, 128B apart (idx g*32)
  unsigned* genv = bar + 320;    // 8 packed gen counters (32B)

  __syncthreads();

  // hoist this lane's W fragments into registers (static indices -> regalloc)
  s16x8 wr[32];
#pragma unroll
  for (int kidx = 0; kidx < 16; ++kidx) {
    int wb = (kh << 10) + kidx * 64 + (kq << 4);
    wr[2 * kidx]     = *(const s16x8*)(wbase + (cc0 << 11) + (wb ^ xr));
    wr[2 * kidx + 1] = *(const s16x8*)(wbase + (cc1 << 11) + (wb ^ xr));
  }

  for (int s = 0; s < SEQ; ++s) {
    const unsigned short* hi_in = (s & 1) ? h1hi : h0hi;
    unsigned short* hi_out = (s & 1) ? h0hi : h1hi;
    unsigned long long hadr = (unsigned long long)hi_in + hvoff;

    // gi prefetch (independent of h -> issue before barrier spin)
    float gir = 0.f, giz = 0.f, gin_ = 0.f;
    unsigned short g16r = 0, g16z = 0, g16n = 0;
    if (gi_is_f32) {
      unsigned long long ga = (unsigned long long)(gi32 + (size_t)(s * BATCH + b2) * G3 + j);
      asm volatile("global_load_dword %0, %1, off" : "=v"(gir) : "v"(ga));
      asm volatile("global_load_dword %0, %1, off" : "=v"(giz) : "v"(ga + 4096ull));
      asm volatile("global_load_dword %0, %1, off" : "=v"(gin_) : "v"(ga + 8192ull));
    } else {
      unsigned long long ga = (unsigned long long)(gi16 + (size_t)(s * BATCH + b2) * G3 + j);
      asm volatile("global_load_ushort %0, %1, off" : "=v"(g16r) : "v"(ga));
      asm volatile("global_load_ushort %0, %1, off" : "=v"(g16z) : "v"(ga + 2048ull));
      asm volatile("global_load_ushort %0, %1, off" : "=v"(g16n) : "v"(ga + 4096ull));
    }

    // grid barrier wait: all 8 genv >= s (two b128 sc0sc1 loads per poll)
    if (tid == 0) {
      unsigned long long gva = (unsigned long long)genv;
      for (;;) {
        uint4 g01, g23;
        asm volatile("global_load_dwordx4 %0, %2, off sc0 sc1\n\t"
                     "global_load_dwordx4 %1, %2, off offset:16 sc0 sc1\n\t"
                     "s_waitcnt vmcnt(0)"
                     : "=v"(g01), "=v"(g23) : "v"(gva) : "memory");
        unsigned mn = umin2(umin2(umin2(g01.x, g01.y), umin2(g01.z, g01.w)),
                            umin2(umin2(g23.x, g23.y), umin2(g23.z, g23.w)));
        if (mn >= (unsigned)s) break;
      }
    }
    __syncthreads();

    // pipelined h loads (sc0 sc1) + MFMA, both MFMA operands in VGPRs
    f32x4 acc0 = {0.f, 0.f, 0.f, 0.f}, acc1 = {0.f, 0.f, 0.f, 0.f};
    s16x8 a0, a1, a2, a3, a4, a5, a6, a7, a8, a9, a10, a11, a12, a13, a14, a15;
    LDH(a0, "0");    LDH(a1, "64");   LDH(a2, "128");  LDH(a3, "192");
    LDH(a4, "256");  LDH(a5, "320");  LDH(a6, "384");  LDH(a7, "448");
    LDH(a8, "512");  LDH(a9, "576");  LDH(a10, "640"); LDH(a11, "704");
    LDH(a12, "768"); LDH(a13, "832"); LDH(a14, "896"); LDH(a15, "960");
    WAITV(12);
    MMK(a0, 0); MMK(a1, 1); MMK(a2, 2); MMK(a3, 3);
    WAITV(8);
    MMK(a4, 4); MMK(a5, 5); MMK(a6, 6); MMK(a7, 7);
    WAITV(4);
    MMK(a8, 8); MMK(a9, 9); MMK(a10, 10); MMK(a11, 11);
    WAITV(0);
    MMK(a12, 12); MMK(a13, 13); MMK(a14, 14); MMK(a15, 15);

#pragma unroll
    for (int q = 0; q < 4; ++q)
      ghl2[kh][mt * 16 + kq * 4 + q][row16] = acc0[q];
    if (row16 < 8) {
#pragma unroll
      for (int q = 0; q < 4; ++q)
        ghl2[kh][mt * 16 + kq * 4 + q][16 + row16] = acc1[q];
    }
    __syncthreads();

    // gating
    float ir, iz, inn;
    if (gi_is_f32) { ir = gir; iz = giz; inn = gin_; }
    else { ir = bf2f(g16r); iz = bf2f(g16z); inn = bf2f(g16n); }
    float hr = ghl2[0][b2][u]      + ghl2[1][b2][u]      + bh_r;
    float hz = ghl2[0][b2][8 + u]  + ghl2[1][b2][8 + u]  + bh_z;
    float hn = ghl2[0][b2][16 + u] + ghl2[1][b2][16 + u] + bh_n;
    float r = 1.f / (1.f + __expf(-(ir + hr)));
    float z = 1.f / (1.f + __expf(-(iz + hz)));
    float n = tanhf(inn + r * hn);
    float hp = hown[tid];
    float h = (1.f - z) * n + z * hp;
    hown[tid] = h;
    // h store FIRST (gates the barrier), then out/hidden (drain later)
    unsigned short hb = f2bf(h);
    unsigned hv = (unsigned)(b2 * 1024 + j) * 2u;
    unsigned long long sha = (unsigned long long)hi_out + hv;
    asm volatile("global_store_short %0, %1, off sc0 sc1" :: "v"(sha), "v"(hb) : "memory");
    out[((size_t)b2 * SEQ + s) * HID + j] = h;
    if (s == SEQ - 1) hidden[(size_t)b2 * HID + j] = h;
    // wait only for the h store (oldest); the out store may keep draining
    asm volatile("s_waitcnt vmcnt(1)" ::: "memory");
    __syncthreads();

    // grid barrier arrive: relaxed monotonic; group-complete writes genv[g]
    if (tid == 0) {
      int g = wg & 7;
      unsigned a = __hip_atomic_fetch_add(&cA[g * 32], 1u, __ATOMIC_RELAXED, __HIP_MEMORY_SCOPE_AGENT);
      if (a + 1u == 16u * (unsigned)(s + 1)) {
        __hip_atomic_store(&genv[g], (unsigned)(s + 1), __ATOMIC_RELAXED, __HIP_MEMORY_SCOPE_AGENT);
      }
    }
  }
}

extern "C" void kernel_launch(void* const* d_in, const int* in_sizes, int n_in,
                              void* d_out, int out_size, void* d_ws, size_t ws_size,
                              hipStream_t stream) {
  const float* emb = (const float*)d_in[0];
  const float* wih = (const float*)d_in[1];
  const float* whh = (const float*)d_in[2];
  const float* bih = (const float*)d_in[3];
  const float* bhh = (const float*)d_in[4];
  float* out = (float*)d_out;                          // [64][512][1024]
  float* hidden = out + (size_t)BATCH * SEQ * HID;     // [64][1024]

  char* ws = (char*)d_ws;
  size_t off = 0;
  auto alloc = [&](size_t bytes) {
    char* p = ws + off;
    off += (bytes + 255) & ~(size_t)255;
    return p;
  };

  unsigned short* emb_hi = (unsigned short*)alloc((size_t)MTOT * IN_DIM * 2);
  unsigned short* emb_lo = (unsigned short*)alloc((size_t)MTOT * IN_DIM * 2);
  unsigned short* wih_hi = (unsigned short*)alloc((size_t)G3 * IN_DIM * 2);
  unsigned short* wih_lo = (unsigned short*)alloc((size_t)G3 * IN_DIM * 2);
  unsigned short* whh_hi = (unsigned short*)alloc((size_t)G3 * HID * 2);
  unsigned short* whh_lo = (unsigned short*)alloc((size_t)G3 * HID * 2);
  unsigned short* hbuf   = (unsigned short*)alloc((size_t)2 * BATCH * HID * 2);
  unsigned* bar = (unsigned*)alloc(4096);

  size_t gi32_bytes = (size_t)MTOT * G3 * 4;
  int gi_is_f32 = (off + gi32_bytes <= ws_size) ? 1 : 0;
  float* gi32 = nullptr;
  unsigned short* gi16 = nullptr;
  if (gi_is_f32) gi32 = (float*)alloc(gi32_bytes);
  else           gi16 = (unsigned short*)alloc((size_t)MTOT * G3 * 2);

  // converts
  split_kernel<<<4096, 256, 0, stream>>>(emb, emb_hi, emb_lo, MTOT * IN_DIM / 4);
  split_kernel<<<1536, 256, 0, stream>>>(wih, wih_hi, wih_lo, G3 * IN_DIM / 4);
  split_kernel<<<3072, 256, 0, stream>>>(whh, whh_hi, whh_lo, G3 * HID / 4);

  // zero h state (h0 = 0) + barrier state (counters must restart at 0 every call)
  (void)hipMemsetAsync(hbuf, 0, (size_t)2 * BATCH * HID * 2, stream);
  (void)hipMemsetAsync(bar, 0, 4096, stream);

  // phase 1 GEMM
  dim3 g1(MTOT / 128, G3 / 128);
  gemm_gi<<<g1, 256, 0, stream>>>(emb_hi, emb_lo, wih_hi, wih_lo, bih, gi32, gi16, gi_is_f32);

  // persistent scan (cooperative: guarantees all 128 WGs co-resident)
  size_t BH = (size_t)BATCH * HID;
  unsigned short* h0hi = hbuf;
  unsigned short* h1hi = hbuf + BH;
  void* args[] = { &whh_hi, &gi32, &gi16, &gi_is_f32, &bhh,
                   &h0hi, &h1hi, &bar, &out, &hidden };
  (void)hipLaunchCooperativeKernel((void*)gru_persist, dim3(NWG), dim3(512), args, 0, stream);
}